// Round 2
// baseline (34367.581 us; speedup 1.0000x reference)
//
#include <hip/hip_runtime.h>
#include <cmath>

// ---------------------------------------------------------------------------
// GridGRU on MI355X. Round 2: correctness-first f32, ws footprint 134.5 MB.
// Sizes fixed: N=32, T=512, D=H=1024. weight (2048, 6144) row-major, bias 6144.
// ---------------------------------------------------------------------------

#define NT 16384      // N*T
#define HD 1024
#define LDW 6144
#define CT 128        // gates chunk timesteps

__device__ __forceinline__ float sigf(float v) { return 1.f / (1.f + __expf(-v)); }

// ---------------------------------------------------------------------------
// Tiled f32 GEMM. BM=128, BN=64, BK=16, 256 threads, 8x4 acc per thread.
// AMODE: 0 = A1 + row*lda
//        1 = gates mode: A row = x[(row&31)*512 + t0 + (row>>5)], lda=1024
//        2 = concat-K:  k<1024 -> A1[row*1024+k], else A2[row*1024+k-1024]
// EMODE: 0 = C[m*ldc+j] = acc + bias[j]
//        1 = s = sigmoid(acc+bias[j]); j<1024 -> UD[m*1024+j]=s
//                                      else   -> C[m*1024+j-1024] = s * X[...]
//        2 = hc = tanh(acc+bias[j]); C[m*1024+j] = X + UD*(hc - X)
// ---------------------------------------------------------------------------
template<int AMODE, int EMODE>
__global__ __launch_bounds__(256)
void gemm_k(const float* __restrict__ A1, const float* __restrict__ A2,
            int lda, int t0,
            const float* __restrict__ B,
            float* __restrict__ C, int ldc,
            const float* __restrict__ bias,
            const float* __restrict__ X,
            float* __restrict__ UD,
            int K)
{
    __shared__ float As[16][128];
    __shared__ float Bs[16][64];
    const int tid = threadIdx.x;
    const long m_base = (long)blockIdx.y * 128;
    const long n_base = (long)blockIdx.x * 64;
    const int tx = tid & 15;
    const int ty = tid >> 4;

    float acc[8][4];
#pragma unroll
    for (int i = 0; i < 8; ++i)
#pragma unroll
        for (int j = 0; j < 4; ++j) acc[i][j] = 0.f;

    const int m0 = tid >> 2,        c0 = (tid & 3) * 4;          // rows 0..63
    const int m1 = (tid + 256) >> 2, c1 = c0;                    // rows 64..127

    auto loadA4 = [&](long row, int k) -> float4 {
        if (AMODE == 0) return *(const float4*)&A1[row * lda + k];
        if (AMODE == 1) {
            long r = ((row & 31) * 512) + t0 + (row >> 5);
            return *(const float4*)&A1[r * 1024 + k];
        }
        if (k < 1024) return *(const float4*)&A1[row * 1024 + k];
        return *(const float4*)&A2[row * 1024 + (k - 1024)];
    };

    for (int k0 = 0; k0 < K; k0 += 16) {
        float4 a0 = loadA4(m_base + m0, k0 + c0);
        float4 a1 = loadA4(m_base + m1, k0 + c1);
        float4 b  = *(const float4*)&B[(long)(k0 + ty) * LDW + n_base + tx * 4];
        __syncthreads();   // prior iteration's LDS reads done
        As[c0 + 0][m0] = a0.x; As[c0 + 1][m0] = a0.y;
        As[c0 + 2][m0] = a0.z; As[c0 + 3][m0] = a0.w;
        As[c1 + 0][m1] = a1.x; As[c1 + 1][m1] = a1.y;
        As[c1 + 2][m1] = a1.z; As[c1 + 3][m1] = a1.w;
        *(float4*)&Bs[ty][tx * 4] = b;
        __syncthreads();
#pragma unroll
        for (int k = 0; k < 16; ++k) {
            float4 bv  = *(const float4*)&Bs[k][tx * 4];
            float4 av0 = *(const float4*)&As[k][ty * 8];
            float4 av1 = *(const float4*)&As[k][ty * 8 + 4];
            float av[8] = {av0.x, av0.y, av0.z, av0.w, av1.x, av1.y, av1.z, av1.w};
            float bb[4] = {bv.x, bv.y, bv.z, bv.w};
#pragma unroll
            for (int i = 0; i < 8; ++i)
#pragma unroll
                for (int j = 0; j < 4; ++j)
                    acc[i][j] = fmaf(av[i], bb[j], acc[i][j]);
        }
    }

    const int j0 = (int)n_base + tx * 4;
    float4 bv4 = *(const float4*)&bias[j0];
#pragma unroll
    for (int i = 0; i < 8; ++i) {
        long m = m_base + ty * 8 + i;
        float v0 = acc[i][0] + bv4.x, v1 = acc[i][1] + bv4.y;
        float v2 = acc[i][2] + bv4.z, v3 = acc[i][3] + bv4.w;
        if (EMODE == 0) {
            float4 o = {v0, v1, v2, v3};
            *(float4*)&C[m * ldc + j0] = o;
        } else if (EMODE == 1) {
            float s0 = sigf(v0), s1 = sigf(v1), s2 = sigf(v2), s3 = sigf(v3);
            if (j0 < 1024) {
                float4 o = {s0, s1, s2, s3};
                *(float4*)&UD[m * 1024 + j0] = o;
            } else {
                int jj = j0 - 1024;
                float4 xv = *(const float4*)&X[m * 1024 + jj];
                float4 o = {s0 * xv.x, s1 * xv.y, s2 * xv.z, s3 * xv.w};
                *(float4*)&C[m * 1024 + jj] = o;
            }
        } else {
            float4 xv = *(const float4*)&X[m * 1024 + j0];
            float4 ud = *(const float4*)&UD[m * 1024 + j0];
            float4 o;
            o.x = xv.x + ud.x * (tanhf(v0) - xv.x);
            o.y = xv.y + ud.y * (tanhf(v1) - xv.y);
            o.z = xv.z + ud.z * (tanhf(v2) - xv.z);
            o.w = xv.w + ud.w * (tanhf(v3) - xv.w);
            *(float4*)&C[m * 1024 + j0] = o;
        }
    }
}

// ---------------- scan kernel 1: ur = sigmoid(g1 + h @ Whtg) ----------------
// grid (64, 2) x 512 thr: x = 32-col j tile of [0,2048); y = batch half (16 rows).
__global__ __launch_bounds__(512)
void scan_ur(const float* __restrict__ gates_c,   // chunk [CT*32][3072]
             const float* __restrict__ hbase, long hstride,
             const float* __restrict__ W,          // Whtg col base
             float* __restrict__ u,                // [32,1024]
             float* __restrict__ rh,               // [32,1024]
             int tl)
{
    __shared__ float hs[16 * 1024];                // 64 KiB
    const int tid = threadIdx.x;
    const int rbase = blockIdx.y * 16;
    for (int idx = tid; idx < 4096; idx += 512) {
        int r = idx >> 8, c = (idx & 255) * 4;
        *(float4*)&hs[r * 1024 + c] =
            *(const float4*)&hbase[(long)(rbase + r) * hstride + c];
    }
    __syncthreads();

    const int j  = blockIdx.x * 32 + (tid & 31);
    const int rl = tid >> 5;            // 0..15
    const int n  = rbase + rl;
    const float* h = &hs[rl * 1024];
    const float* w = W + j;
    float acc = 0.f;
#pragma unroll 8
    for (int k = 0; k < 1024; ++k) acc = fmaf(h[k], w[(long)k * LDW], acc);

    float p = gates_c[((long)tl * 32 + n) * 3072 + j] + acc;
    float s = sigf(p);
    if (j < 1024) u[n * 1024 + j] = s;
    else          rh[n * 1024 + (j - 1024)] = s * h[j - 1024];
}

// ------- scan kernel 2: hc = tanh(g2 + rh @ Wsmall); h' = h + u(hc-h) -------
// grid (32, 2) x 512 thr.
__global__ __launch_bounds__(512)
void scan_hc(const float* __restrict__ gates_c,
             const float* __restrict__ hbase, long hstride,
             const float* __restrict__ Wsm,
             const float* __restrict__ u, const float* __restrict__ rh,
             float* __restrict__ hout,             // ht + t*1024 (row stride 512*1024)
             int tl)
{
    __shared__ float rs[16 * 1024];
    const int tid = threadIdx.x;
    const int rbase = blockIdx.y * 16;
    for (int idx = tid; idx < 4096; idx += 512) {
        int r = idx >> 8, c = (idx & 255) * 4;
        *(float4*)&rs[r * 1024 + c] = *(const float4*)&rh[(long)(rbase + r) * 1024 + c];
    }
    __syncthreads();

    const int j  = blockIdx.x * 32 + (tid & 31);   // 0..1023
    const int rl = tid >> 5;
    const int n  = rbase + rl;
    const float* rr = &rs[rl * 1024];
    const float* w = Wsm + j;
    float acc = 0.f;
#pragma unroll 8
    for (int k = 0; k < 1024; ++k) acc = fmaf(rr[k], w[(long)k * LDW], acc);

    float p  = gates_c[((long)tl * 32 + n) * 3072 + 2048 + j] + acc;
    float hc = tanhf(p);
    float h0 = hbase[(long)n * hstride + j];
    float uu = u[n * 1024 + j];
    hout[(long)n * (512 * 1024) + j] = h0 + uu * (hc - h0);
}

__global__ __launch_bounds__(256)
void last_h_copy(const float* __restrict__ ht, float* __restrict__ dst)
{
    int i = blockIdx.x * 256 + threadIdx.x;   // 32768
    int n = i >> 10, k = i & 1023;
    dst[i] = ht[((long)(n * 512 + 511)) * 1024 + k];
}

// ---------------------------------------------------------------------------
extern "C" void kernel_launch(void* const* d_in, const int* in_sizes, int n_in,
                              void* d_out, int out_size, void* d_ws, size_t ws_size,
                              hipStream_t stream)
{
    const float* x       = (const float*)d_in[0];
    const float* prev_ht = (const float*)d_in[1];
    const float* weight  = (const float*)d_in[2];
    const float* bias    = (const float*)d_in[3];
    float* out = (float*)d_out;
    float* ws  = (float*)d_ws;

    // ws layout (floats):
    float* region0 = ws;                  // 16,777,216: gates chunk (12.6M) / rx
    float* ht      = ws + 16777216;       // 16,777,216
    float* u_buf   = ws + 33554432;       // 32,768
    float* rh_buf  = ws + 33554432 + 32768;
    const size_t needed = (size_t)(33554432 + 65536) * sizeof(float); // 134.5 MB
    if (ws_size < needed) return;         // diagnostic guard: clean fail, no OOB

    const float* Whtg   = weight + (long)1024 * LDW;          // rows 1024.., cols 0..2047
    const float* Wsmall = weight + (long)1024 * LDW + 2048;   // cols 2048..3071

    // scan in 4 segments: gates chunk GEMM, then 128 steps
    for (int seg = 0; seg < 4; ++seg) {
        int t0 = seg * CT;
        dim3 g0(3072 / 64, CT * 32 / 128);
        gemm_k<1, 0><<<g0, 256, 0, stream>>>(x, nullptr, 1024, t0, weight,
                                             region0, 3072, bias, nullptr, nullptr, 1024);
        for (int tl = 0; tl < CT; ++tl) {
            int t = t0 + tl;
            const float* hb = (t == 0) ? prev_ht : (ht + (long)(t - 1) * 1024);
            long hstr = (t == 0) ? 1024L : 512L * 1024L;
            scan_ur<<<dim3(64, 2), 512, 0, stream>>>(region0, hb, hstr, Whtg,
                                                     u_buf, rh_buf, tl);
            scan_hc<<<dim3(32, 2), 512, 0, stream>>>(region0, hb, hstr, Wsmall,
                                                     u_buf, rh_buf,
                                                     ht + (long)t * 1024, tl);
        }
    }

    // depth phase (region0 now reused as rx)
    float* rx = region0;
    // urd: concat [x | ht] @ weight[:, 3072:5120] + bd -> sigmoid
    //      j<1024: ud -> d_out staging; j>=1024: rx = r*x
    gemm_k<2, 1><<<dim3(2048 / 64, NT / 128), 256, 0, stream>>>(
        x, ht, 1024, 0, weight + 3072, rx, 1024, bias + 3072, x, out, 2048);
    // hcd: concat [rx | ht] @ weight[:, 5120:6144] + bd2 -> tanh -> final out
    gemm_k<2, 2><<<dim3(1024 / 64, NT / 128), 256, 0, stream>>>(
        rx, ht, 1024, 0, weight + 5120, out, 1024, bias + 5120, x, out, 2048);

    last_h_copy<<<32768 / 256, 256, 0, stream>>>(ht, out + (long)NT * HD);
}